// Round 1
// baseline (542.028 us; speedup 1.0000x reference)
//
#include <hip/hip_runtime.h>
#include <stdint.h>

typedef unsigned short u16;
typedef __attribute__((ext_vector_type(8))) short short8;
typedef __attribute__((ext_vector_type(4))) float f32x4;

#define NEG_F (-3.402823466e+38f)

__device__ __forceinline__ u16 f2bf(float x) {
    uint32_t u = __builtin_bit_cast(uint32_t, x);
    u = (u + 0x7fffu + ((u >> 16) & 1u)) >> 16;
    return (u16)u;
}
__device__ __forceinline__ float bf2f(u16 b) {
    uint32_t u = ((uint32_t)b) << 16;
    return __builtin_bit_cast(float, u);
}

__device__ __forceinline__ void gload_lds16(const void* g, void* l) {
    __builtin_amdgcn_global_load_lds((const __attribute__((address_space(1))) void*)g,
                                     (__attribute__((address_space(3))) void*)l, 16, 0, 0);
}

// ---------------------------------------------------------------------------
// FPS: one block per batch, 1024 threads, 8 points/thread (strided), serial
// 128-iteration farthest-point sampling with JAX argmax tie semantics
// (first index wins).
// ---------------------------------------------------------------------------
__global__ __launch_bounds__(1024) void fps_kernel(const float* __restrict__ coords,
                                                   const float* __restrict__ times,
                                                   float* __restrict__ cent_ws,
                                                   float* __restrict__ cent_out,
                                                   float* __restrict__ mask_out) {
    const int b = blockIdx.x;
    const int tid = threadIdx.x;
    const int lane = tid & 63;
    const int wid = tid >> 6;  // 0..15

    float px[8], py[8], pz[8], pw[8], md[8];
    float sx = 0.f, sy = 0.f, sz = 0.f, sw = 0.f;
#pragma unroll
    for (int j = 0; j < 8; ++j) {
        const int p = j * 1024 + tid;
        const int n = b * 8192 + p;
        px[j] = coords[3 * n + 0];
        py[j] = coords[3 * n + 1];
        pz[j] = coords[3 * n + 2];
        pw[j] = times[n];
        md[j] = __builtin_inff();
        sx += px[j]; sy += py[j]; sz += pz[j]; sw += pw[j];
    }

    __shared__ float redv[16][4];
    __shared__ float rbv[16];
    __shared__ int rbi[16];
    __shared__ float cbuf[4];
    __shared__ int selbuf;

#pragma unroll
    for (int off = 32; off > 0; off >>= 1) {
        sx += __shfl_down(sx, off);
        sy += __shfl_down(sy, off);
        sz += __shfl_down(sz, off);
        sw += __shfl_down(sw, off);
    }
    if (lane == 0) { redv[wid][0] = sx; redv[wid][1] = sy; redv[wid][2] = sz; redv[wid][3] = sw; }
    __syncthreads();
    if (tid == 0) {
        float mx = 0.f, my = 0.f, mz = 0.f, mw = 0.f;
        for (int w = 0; w < 16; ++w) { mx += redv[w][0]; my += redv[w][1]; mz += redv[w][2]; mw += redv[w][3]; }
        cbuf[0] = mx * (1.0f / 8192.0f);
        cbuf[1] = my * (1.0f / 8192.0f);
        cbuf[2] = mz * (1.0f / 8192.0f);
        cbuf[3] = mw * (1.0f / 8192.0f);
    }
    __syncthreads();
    const float mnx = cbuf[0], mny = cbuf[1], mnz = cbuf[2], mnw = cbuf[3];

    for (int t = 0; t < 128; ++t) {
        float v = -__builtin_inff();
        int idx = 0;
        if (t == 0) {
#pragma unroll
            for (int j = 0; j < 8; ++j) {
                const float dx = px[j] - mnx, dy = py[j] - mny, dz = pz[j] - mnz, dw = pw[j] - mnw;
                const float d2 = dx * dx + dy * dy + dz * dz + dw * dw;
                if (d2 > v) { v = d2; idx = j * 1024 + tid; }
            }
        } else {
            const float c0 = cbuf[0], c1 = cbuf[1], c2 = cbuf[2], c3 = cbuf[3];
#pragma unroll
            for (int j = 0; j < 8; ++j) {
                const float dx = px[j] - c0, dy = py[j] - c1, dz = pz[j] - c2, dw = pw[j] - c3;
                const float d2 = dx * dx + dy * dy + dz * dz + dw * dw;
                const float nm = fminf(md[j], d2);
                md[j] = nm;
                if (nm > v) { v = nm; idx = j * 1024 + tid; }
            }
        }
#pragma unroll
        for (int off = 32; off > 0; off >>= 1) {
            const float ov = __shfl_down(v, off);
            const int oi = __shfl_down(idx, off);
            if (ov > v || (ov == v && oi < idx)) { v = ov; idx = oi; }
        }
        if (lane == 0) { rbv[wid] = v; rbi[wid] = idx; }
        __syncthreads();
        if (tid == 0) {
            float bb = rbv[0]; int bi = rbi[0];
            for (int w = 1; w < 16; ++w)
                if (rbv[w] > bb || (rbv[w] == bb && rbi[w] < bi)) { bb = rbv[w]; bi = rbi[w]; }
            selbuf = bi;
        }
        __syncthreads();
        const int sel = selbuf;
        if (tid == (sel & 1023)) {
            const int js = sel >> 10;
            float cx = 0.f, cy = 0.f, cz = 0.f, cw = 0.f;
#pragma unroll
            for (int j = 0; j < 8; ++j) {
                if (j == js) { cx = px[j]; cy = py[j]; cz = pz[j]; cw = pw[j]; md[j] = NEG_F; }
            }
            cbuf[0] = cx; cbuf[1] = cy; cbuf[2] = cz; cbuf[3] = cw;
            const int o = (b * 128 + t) * 4;
            cent_ws[o + 0] = cx; cent_ws[o + 1] = cy; cent_ws[o + 2] = cz; cent_ws[o + 3] = cw;
            cent_out[o + 0] = cx; cent_out[o + 1] = cy; cent_out[o + 2] = cz; cent_out[o + 3] = cw;
        }
        __syncthreads();
    }
    if (tid < 128) mask_out[b * 128 + tid] = 1.0f;
}

// ---------------------------------------------------------------------------
// KNN: one block per centroid (B*T=1024 blocks). d2 in LDS, 16 rounds of
// block argmin with lower-index tie-break (matches lax.top_k on -d2).
// d2 = c2 + p2 - 2*dot  (same formula as the reference).
// ---------------------------------------------------------------------------
__global__ __launch_bounds__(256) void knn_kernel(const float* __restrict__ coords,
                                                  const float* __restrict__ times,
                                                  const float* __restrict__ cent,
                                                  int* __restrict__ knn) {
    __shared__ float d2s[8192];
    __shared__ float rbv[4];
    __shared__ int rbi[4];
    const int q = blockIdx.x;
    const int b = q >> 7;
    const int tid = threadIdx.x;
    const int lane = tid & 63;
    const int wid = tid >> 6;
    const float c0 = cent[q * 4 + 0], c1 = cent[q * 4 + 1], c2 = cent[q * 4 + 2], c3 = cent[q * 4 + 3];
    const float cc = c0 * c0 + c1 * c1 + c2 * c2 + c3 * c3;
    for (int p = tid; p < 8192; p += 256) {
        const int n = b * 8192 + p;
        const float x0 = coords[3 * n], x1 = coords[3 * n + 1], x2 = coords[3 * n + 2], x3 = times[n];
        const float pp = x0 * x0 + x1 * x1 + x2 * x2 + x3 * x3;
        const float dt = x0 * c0 + x1 * c1 + x2 * c2 + x3 * c3;
        d2s[p] = cc + pp - 2.0f * dt;
    }
    __syncthreads();
    for (int r = 0; r < 16; ++r) {
        float v = __builtin_inff();
        int idx = 1 << 30;
        for (int s = 0; s < 32; ++s) {
            const int p = s * 256 + tid;
            const float d = d2s[p];
            if (d < v) { v = d; idx = p; }
        }
#pragma unroll
        for (int off = 32; off > 0; off >>= 1) {
            const float ov = __shfl_down(v, off);
            const int oi = __shfl_down(idx, off);
            if (ov < v || (ov == v && oi < idx)) { v = ov; idx = oi; }
        }
        if (lane == 0) { rbv[wid] = v; rbi[wid] = idx; }
        __syncthreads();
        if (tid == 0) {
            float bb = rbv[0]; int bi = rbi[0];
            for (int w = 1; w < 4; ++w)
                if (rbv[w] < bb || (rbv[w] == bb && rbi[w] < bi)) { bb = rbv[w]; bi = rbi[w]; }
            knn[q * 16 + r] = bi;
            d2s[bi] = __builtin_inff();
        }
        __syncthreads();
    }
}

// ---------------------------------------------------------------------------
// Gather features for the 16384 knn rows into bf16 A0 (K padded 32->64 with 0)
// ---------------------------------------------------------------------------
__global__ __launch_bounds__(256) void gather_kernel(const float* __restrict__ feat,
                                                     const int* __restrict__ knn,
                                                     u16* __restrict__ A0) {
    const int idx = blockIdx.x * 256 + threadIdx.x;  // 16384*64
    const int g = idx >> 6;
    const int c = idx & 63;
    const int b = g >> 11;  // g / (T*K)=g/2048
    const int n = b * 8192 + knn[g];
    const float v = (c < 32) ? feat[(size_t)n * 32 + c] : 0.0f;
    A0[idx] = f2bf(v);
}

// Transpose weight (K,N) f32 -> (N,Kpad) bf16, zero-padded in K.
__global__ __launch_bounds__(256) void transpose_w(const float* __restrict__ W,
                                                   u16* __restrict__ Wt,
                                                   int K, int N, int Kpad) {
    const int idx = blockIdx.x * 256 + threadIdx.x;  // N*Kpad
    const int n = idx / Kpad;
    const int k = idx - n * Kpad;
    const float v = (k < K) ? W[(size_t)k * N + n] : 0.0f;
    Wt[idx] = f2bf(v);
}

// Max-pool over K=16 gathered rows: PF (16384,768) bf16 -> pooled (1024,768)
__global__ __launch_bounds__(256) void pool_kernel(const u16* __restrict__ PF,
                                                   u16* __restrict__ pooled) {
    const int idx = blockIdx.x * 256 + threadIdx.x;  // 1024*768
    const int q = idx / 768;
    const int c = idx - q * 768;
    const u16* base = PF + (size_t)q * 16 * 768 + c;
    float best = -__builtin_inff();
    u16 bb = 0;
#pragma unroll
    for (int kk = 0; kk < 16; ++kk) {
        const u16 u = base[kk * 768];
        const float f = bf2f(u);
        if (f > best) { best = f; bb = u; }
    }
    pooled[idx] = bb;
}

// ---------------------------------------------------------------------------
// bf16 MFMA GEMM: C(M,N) = relu?(A(M,K) @ W(K,N) + bias), W given as Wt(N,K).
// 128x128 tile, BK=64, 4 waves (2x2 of 64x64), global_load_lds width 16,
// source-side XOR swizzle so ds_read_b128 is ~conflict-free.
// ---------------------------------------------------------------------------
template <int RELU, int OUTF32>
__global__ __launch_bounds__(256) void gemm_kernel(const u16* __restrict__ A,
                                                   const u16* __restrict__ Bt,
                                                   const float* __restrict__ bias,
                                                   void* __restrict__ Cv,
                                                   int M, int N, int K) {
    (void)M;
    __shared__ __align__(16) u16 As[128 * 64];
    __shared__ __align__(16) u16 Bs[128 * 64];
    const int tid = threadIdx.x;
    const int lane = tid & 63;
    const int wid = tid >> 6;
    const int brow = blockIdx.x * 128;
    const int bcol = blockIdx.y * 128;
    const int wm = (wid >> 1) * 64;
    const int wn = (wid & 1) * 64;

    f32x4 acc[4][4];
#pragma unroll
    for (int m = 0; m < 4; ++m)
#pragma unroll
        for (int n = 0; n < 4; ++n)
            acc[m][n] = f32x4{0.f, 0.f, 0.f, 0.f};

    const int srow = tid >> 3;    // 0..31
    const int schunk = tid & 7;   // 16B chunk within a 128B row
    const uint32_t lds_wave_base = (uint32_t)(wid * 1024);

    for (int k0 = 0; k0 < K; k0 += 64) {
#pragma unroll
        for (int i = 0; i < 4; ++i) {
            const int row = i * 32 + srow;
            const int sc = schunk ^ (row & 7);  // inverse-swizzled SOURCE chunk
            const u16* ga = A + (size_t)(brow + row) * K + (size_t)(k0 + sc * 8);
            const u16* gb = Bt + (size_t)(bcol + row) * K + (size_t)(k0 + sc * 8);
            const uint32_t lb = (uint32_t)(i * 4096) + lds_wave_base;  // wave-uniform base
            gload_lds16(ga, (char*)As + lb);
            gload_lds16(gb, (char*)Bs + lb);
        }
        __syncthreads();
#pragma unroll
        for (int kc = 0; kc < 2; ++kc) {
            short8 af[4], bfr[4];
#pragma unroll
            for (int m = 0; m < 4; ++m) {
                const int row = wm + m * 16 + (lane & 15);
                const int sc = (kc * 4 + (lane >> 4)) ^ (row & 7);
                af[m] = *(const short8*)(As + row * 64 + sc * 8);
            }
#pragma unroll
            for (int n = 0; n < 4; ++n) {
                const int row = wn + n * 16 + (lane & 15);
                const int sc = (kc * 4 + (lane >> 4)) ^ (row & 7);
                bfr[n] = *(const short8*)(Bs + row * 64 + sc * 8);
            }
#pragma unroll
            for (int m = 0; m < 4; ++m)
#pragma unroll
                for (int n = 0; n < 4; ++n)
                    acc[m][n] = __builtin_amdgcn_mfma_f32_16x16x32_bf16(af[m], bfr[n], acc[m][n], 0, 0, 0);
        }
        __syncthreads();
    }

#pragma unroll
    for (int m = 0; m < 4; ++m) {
        const int row0 = brow + wm + m * 16 + ((lane >> 4) << 2);
#pragma unroll
        for (int n = 0; n < 4; ++n) {
            const int col = bcol + wn + n * 16 + (lane & 15);
            const float bv = bias[col];
#pragma unroll
            for (int r = 0; r < 4; ++r) {
                float v = acc[m][n][r] + bv;
                if (RELU) v = fmaxf(v, 0.0f);
                if (OUTF32) ((float*)Cv)[(size_t)(row0 + r) * N + col] = v;
                else ((u16*)Cv)[(size_t)(row0 + r) * N + col] = f2bf(v);
            }
        }
    }
}

// ---------------------------------------------------------------------------
extern "C" void kernel_launch(void* const* d_in, const int* in_sizes, int n_in,
                              void* d_out, int out_size, void* d_ws, size_t ws_size,
                              hipStream_t stream) {
    (void)in_sizes; (void)n_in; (void)out_size; (void)ws_size;
    const float* coords = (const float*)d_in[0];
    const float* features = (const float*)d_in[1];
    const float* times = (const float*)d_in[3];
    const float* W0 = (const float*)d_in[4];
    const float* b0 = (const float*)d_in[5];
    const float* W1 = (const float*)d_in[6];
    const float* b1 = (const float*)d_in[7];
    const float* W2 = (const float*)d_in[8];
    const float* b2 = (const float*)d_in[9];
    const float* W3 = (const float*)d_in[10];
    const float* b3 = (const float*)d_in[11];
    const float* Wn0 = (const float*)d_in[12];
    const float* bn0 = (const float*)d_in[13];
    const float* Wn1 = (const float*)d_in[14];
    const float* bn1 = (const float*)d_in[15];

    char* ws = (char*)d_ws;
    float* cent = (float*)(ws + 0);           // 1024*4 f32
    int* knn = (int*)(ws + 16384);            // 16384 int
    u16* W0t = (u16*)(ws + 81920);            // 256x64
    u16* W1t = (u16*)(ws + 114688);           // 512x256
    u16* W2t = (u16*)(ws + 376832);           // 768x512
    u16* W3t = (u16*)(ws + 1163264);          // 768x768
    u16* Wn0t = (u16*)(ws + 2342912);         // 768x768
    u16* Wn1t = (u16*)(ws + 3522560);         // 768x768
    u16* bufX = (u16*)(ws + 4702208);         // 16384x768 bf16 max
    u16* bufY = (u16*)(ws + 29868032);        // 16384x768 bf16 max

    float* tokens_out = (float*)d_out;                    // (8,128,768)
    float* cent_out = (float*)d_out + 786432;             // (8,128,4)
    float* mask_out = (float*)d_out + 786432 + 4096;      // (8,128)

    // weights -> bf16 transposed (N,Kpad)
    transpose_w<<<64, 256, 0, stream>>>(W0, W0t, 32, 256, 64);
    transpose_w<<<512, 256, 0, stream>>>(W1, W1t, 256, 512, 256);
    transpose_w<<<1536, 256, 0, stream>>>(W2, W2t, 512, 768, 512);
    transpose_w<<<2304, 256, 0, stream>>>(W3, W3t, 768, 768, 768);
    transpose_w<<<2304, 256, 0, stream>>>(Wn0, Wn0t, 768, 768, 768);
    transpose_w<<<2304, 256, 0, stream>>>(Wn1, Wn1t, 768, 768, 768);

    // FPS -> centroids (also fills centroid + mask outputs)
    fps_kernel<<<8, 1024, 0, stream>>>(coords, times, cent, cent_out, mask_out);
    // KNN top-16 per centroid
    knn_kernel<<<1024, 256, 0, stream>>>(coords, times, cent, knn);
    // gather knn rows' features (bf16, K padded to 64)
    gather_kernel<<<4096, 256, 0, stream>>>(features, knn, bufX);

    // MLP on gathered rows (M = 16384)
    gemm_kernel<1, 0><<<dim3(128, 2), 256, 0, stream>>>(bufX, W0t, b0, bufY, 16384, 256, 64);
    gemm_kernel<1, 0><<<dim3(128, 4), 256, 0, stream>>>(bufY, W1t, b1, bufX, 16384, 512, 256);
    gemm_kernel<1, 0><<<dim3(128, 6), 256, 0, stream>>>(bufX, W2t, b2, bufY, 16384, 768, 512);
    gemm_kernel<0, 0><<<dim3(128, 6), 256, 0, stream>>>(bufY, W3t, b3, bufX, 16384, 768, 768);

    // max-pool over the 16 neighbors
    pool_kernel<<<3072, 256, 0, stream>>>(bufX, bufY);

    // token MLP (M = 1024)
    gemm_kernel<1, 0><<<dim3(8, 6), 256, 0, stream>>>(bufY, Wn0t, bn0, bufX, 1024, 768, 768);
    gemm_kernel<0, 1><<<dim3(8, 6), 256, 0, stream>>>(bufX, Wn1t, bn1, tokens_out, 1024, 768, 768);
}

// Round 2
// 367.071 us; speedup vs baseline: 1.4766x; 1.4766x over previous
//
#include <hip/hip_runtime.h>
#include <stdint.h>

typedef unsigned short u16;
typedef __attribute__((ext_vector_type(8))) short short8;
typedef __attribute__((ext_vector_type(4))) float f32x4;

#define NEG_F (-3.402823466e+38f)

__device__ __forceinline__ u16 f2bf(float x) {
    uint32_t u = __builtin_bit_cast(uint32_t, x);
    u = (u + 0x7fffu + ((u >> 16) & 1u)) >> 16;
    return (u16)u;
}
__device__ __forceinline__ float bf2f(u16 b) {
    uint32_t u = ((uint32_t)b) << 16;
    return __builtin_bit_cast(float, u);
}

__device__ __forceinline__ void gload_lds16(const void* g, void* l) {
    __builtin_amdgcn_global_load_lds((const __attribute__((address_space(1))) void*)g,
                                     (__attribute__((address_space(3))) void*)l, 16, 0, 0);
}

// One DPP argmax step: pull (v,idx) from another lane per CTRL, keep the
// larger v (ties -> smaller idx). Invalid/masked lanes fall back to self
// (old = self, bound_ctrl=false) so the select is a harmless no-op there.
template <int CTRL, int RMASK>
__device__ __forceinline__ void argmax_dpp_step(float& v, int& i) {
    const int vb = __builtin_bit_cast(int, v);
    const int vv = __builtin_amdgcn_update_dpp(vb, vb, CTRL, RMASK, 0xf, false);
    const int ii = __builtin_amdgcn_update_dpp(i, i, CTRL, RMASK, 0xf, false);
    const float fv = __builtin_bit_cast(float, vv);
    if (fv > v || (fv == v && ii < i)) { v = fv; i = ii; }
}

// Full wave64 argmax -> result lands in lane 63.
__device__ __forceinline__ void argmax_wave(float& v, int& i) {
    argmax_dpp_step<0x111, 0xf>(v, i);  // row_shr:1
    argmax_dpp_step<0x112, 0xf>(v, i);  // row_shr:2
    argmax_dpp_step<0x114, 0xf>(v, i);  // row_shr:4
    argmax_dpp_step<0x118, 0xf>(v, i);  // row_shr:8
    argmax_dpp_step<0x142, 0xa>(v, i);  // row_bcast:15 -> rows 1,3
    argmax_dpp_step<0x143, 0xc>(v, i);  // row_bcast:31 -> rows 2,3
}

// ---------------------------------------------------------------------------
// FPS: one block per batch, 1024 threads, 8 points/thread. One barrier per
// iteration: DPP wave argmax -> lane63 LDS atomicMax into slot[t] (sortable
// key, first-index tie-break) -> barrier -> everyone reads slot[t].
// Distance arithmetic identical to the round-0 version (bit-exact argmax).
// ---------------------------------------------------------------------------
__global__ __launch_bounds__(1024) void fps_kernel(const float* __restrict__ coords,
                                                   const float* __restrict__ times,
                                                   float* __restrict__ cent_ws,
                                                   float* __restrict__ cent_out,
                                                   float* __restrict__ mask_out) {
    const int b = blockIdx.x;
    const int tid = threadIdx.x;
    const int lane = tid & 63;
    const int wid = tid >> 6;  // 0..15

    __shared__ unsigned long long slot[128];
    __shared__ float redv[16][4];
    __shared__ float meanbuf[4];

    float px[8], py[8], pz[8], pw[8], md[8];
    float sx = 0.f, sy = 0.f, sz = 0.f, sw = 0.f;
#pragma unroll
    for (int j = 0; j < 8; ++j) {
        const int p = j * 1024 + tid;
        const int n = b * 8192 + p;
        px[j] = coords[3 * n + 0];
        py[j] = coords[3 * n + 1];
        pz[j] = coords[3 * n + 2];
        pw[j] = times[n];
        md[j] = __builtin_inff();
        sx += px[j]; sy += py[j]; sz += pz[j]; sw += pw[j];
    }
    if (tid < 128) slot[tid] = 0ull;

#pragma unroll
    for (int off = 32; off > 0; off >>= 1) {
        sx += __shfl_down(sx, off);
        sy += __shfl_down(sy, off);
        sz += __shfl_down(sz, off);
        sw += __shfl_down(sw, off);
    }
    if (lane == 0) { redv[wid][0] = sx; redv[wid][1] = sy; redv[wid][2] = sz; redv[wid][3] = sw; }
    __syncthreads();
    if (tid == 0) {
        float mx = 0.f, my = 0.f, mz = 0.f, mw = 0.f;
        for (int w = 0; w < 16; ++w) { mx += redv[w][0]; my += redv[w][1]; mz += redv[w][2]; mw += redv[w][3]; }
        meanbuf[0] = mx * (1.0f / 8192.0f);
        meanbuf[1] = my * (1.0f / 8192.0f);
        meanbuf[2] = mz * (1.0f / 8192.0f);
        meanbuf[3] = mw * (1.0f / 8192.0f);
    }
    __syncthreads();

    float c0 = meanbuf[0], c1 = meanbuf[1], c2 = meanbuf[2], c3 = meanbuf[3];

    for (int t = 0; t < 128; ++t) {
        float v = -__builtin_inff();
        int idx = 0;
        if (t == 0) {
#pragma unroll
            for (int j = 0; j < 8; ++j) {
                const float dx = px[j] - c0, dy = py[j] - c1, dz = pz[j] - c2, dw = pw[j] - c3;
                const float d2 = dx * dx + dy * dy + dz * dz + dw * dw;
                if (d2 > v) { v = d2; idx = j * 1024 + tid; }
            }
        } else {
#pragma unroll
            for (int j = 0; j < 8; ++j) {
                const float dx = px[j] - c0, dy = py[j] - c1, dz = pz[j] - c2, dw = pw[j] - c3;
                const float d2 = dx * dx + dy * dy + dz * dz + dw * dw;
                const float nm = fminf(md[j], d2);
                md[j] = nm;
                if (nm > v) { v = nm; idx = j * 1024 + tid; }
            }
        }
        argmax_wave(v, idx);
        if (lane == 63) {
            const uint32_t bv = __builtin_bit_cast(uint32_t, v);
            const uint32_t mk = (bv & 0x80000000u) ? ~bv : (bv | 0x80000000u);
            const unsigned long long key =
                ((unsigned long long)mk << 32) | (uint32_t)(0x7FFFFFFF - idx);
            atomicMax(&slot[t], key);
        }
        __syncthreads();
        const unsigned long long kk = slot[t];
        const int sel = 0x7FFFFFFF - (int)(uint32_t)(kk & 0xFFFFFFFFull);
        const int sn = b * 8192 + sel;
        c0 = coords[3 * sn + 0];
        c1 = coords[3 * sn + 1];
        c2 = coords[3 * sn + 2];
        c3 = times[sn];
        const bool own = (tid == (sel & 1023));
        const int js = sel >> 10;
#pragma unroll
        for (int j = 0; j < 8; ++j) md[j] = (own && j == js) ? NEG_F : md[j];
        if (tid == 0) {
            const int o = (b * 128 + t) * 4;
            cent_ws[o + 0] = c0; cent_ws[o + 1] = c1; cent_ws[o + 2] = c2; cent_ws[o + 3] = c3;
            cent_out[o + 0] = c0; cent_out[o + 1] = c1; cent_out[o + 2] = c2; cent_out[o + 3] = c3;
        }
    }
    if (tid < 128) mask_out[b * 128 + tid] = 1.0f;
}

// ---------------------------------------------------------------------------
// KNN: one block per centroid (B*T=1024 blocks). d2 in LDS, 16 rounds of
// block argmin with lower-index tie-break (matches lax.top_k on -d2).
// d2 = c2 + p2 - 2*dot  (same formula as the reference).
// ---------------------------------------------------------------------------
__global__ __launch_bounds__(256) void knn_kernel(const float* __restrict__ coords,
                                                  const float* __restrict__ times,
                                                  const float* __restrict__ cent,
                                                  int* __restrict__ knn) {
    __shared__ float d2s[8192];
    __shared__ float rbv[4];
    __shared__ int rbi[4];
    const int q = blockIdx.x;
    const int b = q >> 7;
    const int tid = threadIdx.x;
    const int lane = tid & 63;
    const int wid = tid >> 6;
    const float c0 = cent[q * 4 + 0], c1 = cent[q * 4 + 1], c2 = cent[q * 4 + 2], c3 = cent[q * 4 + 3];
    const float cc = c0 * c0 + c1 * c1 + c2 * c2 + c3 * c3;
    for (int p = tid; p < 8192; p += 256) {
        const int n = b * 8192 + p;
        const float x0 = coords[3 * n], x1 = coords[3 * n + 1], x2 = coords[3 * n + 2], x3 = times[n];
        const float pp = x0 * x0 + x1 * x1 + x2 * x2 + x3 * x3;
        const float dt = x0 * c0 + x1 * c1 + x2 * c2 + x3 * c3;
        d2s[p] = cc + pp - 2.0f * dt;
    }
    __syncthreads();
    for (int r = 0; r < 16; ++r) {
        float v = __builtin_inff();
        int idx = 1 << 30;
        for (int s = 0; s < 32; ++s) {
            const int p = s * 256 + tid;
            const float d = d2s[p];
            if (d < v) { v = d; idx = p; }
        }
#pragma unroll
        for (int off = 32; off > 0; off >>= 1) {
            const float ov = __shfl_down(v, off);
            const int oi = __shfl_down(idx, off);
            if (ov < v || (ov == v && oi < idx)) { v = ov; idx = oi; }
        }
        if (lane == 0) { rbv[wid] = v; rbi[wid] = idx; }
        __syncthreads();
        if (tid == 0) {
            float bb = rbv[0]; int bi = rbi[0];
            for (int w = 1; w < 4; ++w)
                if (rbv[w] < bb || (rbv[w] == bb && rbi[w] < bi)) { bb = rbv[w]; bi = rbi[w]; }
            knn[q * 16 + r] = bi;
            d2s[bi] = __builtin_inff();
        }
        __syncthreads();
    }
}

// ---------------------------------------------------------------------------
// Gather features for the 16384 knn rows into bf16 A0 (K padded 32->64 with 0)
// ---------------------------------------------------------------------------
__global__ __launch_bounds__(256) void gather_kernel(const float* __restrict__ feat,
                                                     const int* __restrict__ knn,
                                                     u16* __restrict__ A0) {
    const int idx = blockIdx.x * 256 + threadIdx.x;  // 16384*64
    const int g = idx >> 6;
    const int c = idx & 63;
    const int b = g >> 11;  // g / (T*K)=g/2048
    const int n = b * 8192 + knn[g];
    const float v = (c < 32) ? feat[(size_t)n * 32 + c] : 0.0f;
    A0[idx] = f2bf(v);
}

// All six weight transposes in ONE launch. Segment boundaries are 256-aligned
// so each block is branch-uniform.
template <int K, int N, int KP>
__device__ __forceinline__ void tp_one(const float* __restrict__ W, u16* __restrict__ Wt, int local) {
    const int n = local / KP;
    const int k = local - n * KP;
    const float v = (k < K) ? W[(size_t)k * N + n] : 0.0f;
    Wt[local] = f2bf(v);
}

__global__ __launch_bounds__(256) void transpose_all(const float* __restrict__ W0,
                                                     const float* __restrict__ W1,
                                                     const float* __restrict__ W2,
                                                     const float* __restrict__ W3,
                                                     const float* __restrict__ Wn0,
                                                     const float* __restrict__ Wn1,
                                                     u16* __restrict__ W0t, u16* __restrict__ W1t,
                                                     u16* __restrict__ W2t, u16* __restrict__ W3t,
                                                     u16* __restrict__ Wn0t, u16* __restrict__ Wn1t) {
    const int idx = blockIdx.x * 256 + threadIdx.x;
    if (idx < 16384) tp_one<32, 256, 64>(W0, W0t, idx);
    else if (idx < 147456) tp_one<256, 512, 256>(W1, W1t, idx - 16384);
    else if (idx < 540672) tp_one<512, 768, 512>(W2, W2t, idx - 147456);
    else if (idx < 1130496) tp_one<768, 768, 768>(W3, W3t, idx - 540672);
    else if (idx < 1720320) tp_one<768, 768, 768>(Wn0, Wn0t, idx - 1130496);
    else tp_one<768, 768, 768>(Wn1, Wn1t, idx - 1720320);
}

// Max-pool over K=16 gathered rows: PF (16384,768) bf16 -> pooled (1024,768)
__global__ __launch_bounds__(256) void pool_kernel(const u16* __restrict__ PF,
                                                   u16* __restrict__ pooled) {
    const int idx = blockIdx.x * 256 + threadIdx.x;  // 1024*768
    const int q = idx / 768;
    const int c = idx - q * 768;
    const u16* base = PF + (size_t)q * 16 * 768 + c;
    float best = -__builtin_inff();
    u16 bb = 0;
#pragma unroll
    for (int kk = 0; kk < 16; ++kk) {
        const u16 u = base[kk * 768];
        const float f = bf2f(u);
        if (f > best) { best = f; bb = u; }
    }
    pooled[idx] = bb;
}

// ---------------------------------------------------------------------------
// bf16 MFMA GEMM: C(M,N) = relu?(A(M,K) @ W(K,N) + bias), W given as Wt(N,K).
// 128x128 tile, BK=64, 4 waves (2x2 of 64x64), global_load_lds width 16,
// source-side XOR swizzle so ds_read_b128 is ~conflict-free.
// ---------------------------------------------------------------------------
template <int RELU, int OUTF32>
__global__ __launch_bounds__(256) void gemm_kernel(const u16* __restrict__ A,
                                                   const u16* __restrict__ Bt,
                                                   const float* __restrict__ bias,
                                                   void* __restrict__ Cv,
                                                   int M, int N, int K) {
    (void)M;
    __shared__ __align__(16) u16 As[128 * 64];
    __shared__ __align__(16) u16 Bs[128 * 64];
    const int tid = threadIdx.x;
    const int lane = tid & 63;
    const int wid = tid >> 6;
    const int brow = blockIdx.x * 128;
    const int bcol = blockIdx.y * 128;
    const int wm = (wid >> 1) * 64;
    const int wn = (wid & 1) * 64;

    f32x4 acc[4][4];
#pragma unroll
    for (int m = 0; m < 4; ++m)
#pragma unroll
        for (int n = 0; n < 4; ++n)
            acc[m][n] = f32x4{0.f, 0.f, 0.f, 0.f};

    const int srow = tid >> 3;    // 0..31
    const int schunk = tid & 7;   // 16B chunk within a 128B row
    const uint32_t lds_wave_base = (uint32_t)(wid * 1024);

    for (int k0 = 0; k0 < K; k0 += 64) {
#pragma unroll
        for (int i = 0; i < 4; ++i) {
            const int row = i * 32 + srow;
            const int sc = schunk ^ (row & 7);  // inverse-swizzled SOURCE chunk
            const u16* ga = A + (size_t)(brow + row) * K + (size_t)(k0 + sc * 8);
            const u16* gb = Bt + (size_t)(bcol + row) * K + (size_t)(k0 + sc * 8);
            const uint32_t lb = (uint32_t)(i * 4096) + lds_wave_base;  // wave-uniform base
            gload_lds16(ga, (char*)As + lb);
            gload_lds16(gb, (char*)Bs + lb);
        }
        __syncthreads();
#pragma unroll
        for (int kc = 0; kc < 2; ++kc) {
            short8 af[4], bfr[4];
#pragma unroll
            for (int m = 0; m < 4; ++m) {
                const int row = wm + m * 16 + (lane & 15);
                const int sc = (kc * 4 + (lane >> 4)) ^ (row & 7);
                af[m] = *(const short8*)(As + row * 64 + sc * 8);
            }
#pragma unroll
            for (int n = 0; n < 4; ++n) {
                const int row = wn + n * 16 + (lane & 15);
                const int sc = (kc * 4 + (lane >> 4)) ^ (row & 7);
                bfr[n] = *(const short8*)(Bs + row * 64 + sc * 8);
            }
#pragma unroll
            for (int m = 0; m < 4; ++m)
#pragma unroll
                for (int n = 0; n < 4; ++n)
                    acc[m][n] = __builtin_amdgcn_mfma_f32_16x16x32_bf16(af[m], bfr[n], acc[m][n], 0, 0, 0);
        }
        __syncthreads();
    }

#pragma unroll
    for (int m = 0; m < 4; ++m) {
        const int row0 = brow + wm + m * 16 + ((lane >> 4) << 2);
#pragma unroll
        for (int n = 0; n < 4; ++n) {
            const int col = bcol + wn + n * 16 + (lane & 15);
            const float bv = bias[col];
#pragma unroll
            for (int r = 0; r < 4; ++r) {
                float v = acc[m][n][r] + bv;
                if (RELU) v = fmaxf(v, 0.0f);
                if (OUTF32) ((float*)Cv)[(size_t)(row0 + r) * N + col] = v;
                else ((u16*)Cv)[(size_t)(row0 + r) * N + col] = f2bf(v);
            }
        }
    }
}

// ---------------------------------------------------------------------------
extern "C" void kernel_launch(void* const* d_in, const int* in_sizes, int n_in,
                              void* d_out, int out_size, void* d_ws, size_t ws_size,
                              hipStream_t stream) {
    (void)in_sizes; (void)n_in; (void)out_size; (void)ws_size;
    const float* coords = (const float*)d_in[0];
    const float* features = (const float*)d_in[1];
    const float* times = (const float*)d_in[3];
    const float* W0 = (const float*)d_in[4];
    const float* b0 = (const float*)d_in[5];
    const float* W1 = (const float*)d_in[6];
    const float* b1 = (const float*)d_in[7];
    const float* W2 = (const float*)d_in[8];
    const float* b2 = (const float*)d_in[9];
    const float* W3 = (const float*)d_in[10];
    const float* b3 = (const float*)d_in[11];
    const float* Wn0 = (const float*)d_in[12];
    const float* bn0 = (const float*)d_in[13];
    const float* Wn1 = (const float*)d_in[14];
    const float* bn1 = (const float*)d_in[15];

    char* ws = (char*)d_ws;
    float* cent = (float*)(ws + 0);           // 1024*4 f32
    int* knn = (int*)(ws + 16384);            // 16384 int
    u16* W0t = (u16*)(ws + 81920);            // 256x64
    u16* W1t = (u16*)(ws + 114688);           // 512x256
    u16* W2t = (u16*)(ws + 376832);           // 768x512
    u16* W3t = (u16*)(ws + 1163264);          // 768x768
    u16* Wn0t = (u16*)(ws + 2342912);         // 768x768
    u16* Wn1t = (u16*)(ws + 3522560);         // 768x768
    u16* bufX = (u16*)(ws + 4702208);         // 16384x768 bf16 max
    u16* bufY = (u16*)(ws + 29868032);        // 16384x768 bf16 max

    float* tokens_out = (float*)d_out;                    // (8,128,768)
    float* cent_out = (float*)d_out + 786432;             // (8,128,4)
    float* mask_out = (float*)d_out + 786432 + 4096;      // (8,128)

    // all weight transposes in one launch
    transpose_all<<<9024, 256, 0, stream>>>(W0, W1, W2, W3, Wn0, Wn1,
                                            W0t, W1t, W2t, W3t, Wn0t, Wn1t);

    // FPS -> centroids (also fills centroid + mask outputs)
    fps_kernel<<<8, 1024, 0, stream>>>(coords, times, cent, cent_out, mask_out);
    // KNN top-16 per centroid
    knn_kernel<<<1024, 256, 0, stream>>>(coords, times, cent, knn);
    // gather knn rows' features (bf16, K padded to 64)
    gather_kernel<<<4096, 256, 0, stream>>>(features, knn, bufX);

    // MLP on gathered rows (M = 16384)
    gemm_kernel<1, 0><<<dim3(128, 2), 256, 0, stream>>>(bufX, W0t, b0, bufY, 16384, 256, 64);
    gemm_kernel<1, 0><<<dim3(128, 4), 256, 0, stream>>>(bufY, W1t, b1, bufX, 16384, 512, 256);
    gemm_kernel<1, 0><<<dim3(128, 6), 256, 0, stream>>>(bufX, W2t, b2, bufY, 16384, 768, 512);
    gemm_kernel<0, 0><<<dim3(128, 6), 256, 0, stream>>>(bufY, W3t, b3, bufX, 16384, 768, 768);

    // max-pool over the 16 neighbors
    pool_kernel<<<3072, 256, 0, stream>>>(bufX, bufY);

    // token MLP (M = 1024)
    gemm_kernel<1, 0><<<dim3(8, 6), 256, 0, stream>>>(bufY, Wn0t, bn0, bufX, 1024, 768, 768);
    gemm_kernel<0, 1><<<dim3(8, 6), 256, 0, stream>>>(bufX, Wn1t, bn1, tokens_out, 1024, 768, 768);
}

// Round 4
// 363.334 us; speedup vs baseline: 1.4918x; 1.0103x over previous
//
#include <hip/hip_runtime.h>
#include <stdint.h>

typedef unsigned short u16;
typedef __attribute__((ext_vector_type(8))) short short8;
typedef __attribute__((ext_vector_type(4))) float f32x4;

#define NEG_F (-3.402823466e+38f)

__device__ __forceinline__ u16 f2bf(float x) {
    uint32_t u = __builtin_bit_cast(uint32_t, x);
    u = (u + 0x7fffu + ((u >> 16) & 1u)) >> 16;
    return (u16)u;
}
__device__ __forceinline__ float bf2f(u16 b) {
    uint32_t u = ((uint32_t)b) << 16;
    return __builtin_bit_cast(float, u);
}

__device__ __forceinline__ void gload_lds16(const void* g, void* l) {
    __builtin_amdgcn_global_load_lds((const __attribute__((address_space(1))) void*)g,
                                     (__attribute__((address_space(3))) void*)l, 16, 0, 0);
}

// One DPP argmax step: pull (v,idx) from another lane per CTRL, keep the
// larger v (ties -> smaller idx).
template <int CTRL, int RMASK>
__device__ __forceinline__ void argmax_dpp_step(float& v, int& i) {
    const int vb = __builtin_bit_cast(int, v);
    const int vv = __builtin_amdgcn_update_dpp(vb, vb, CTRL, RMASK, 0xf, false);
    const int ii = __builtin_amdgcn_update_dpp(i, i, CTRL, RMASK, 0xf, false);
    const float fv = __builtin_bit_cast(float, vv);
    if (fv > v || (fv == v && ii < i)) { v = fv; i = ii; }
}

// Full wave64 argmax -> result lands in lane 63.
__device__ __forceinline__ void argmax_wave(float& v, int& i) {
    argmax_dpp_step<0x111, 0xf>(v, i);  // row_shr:1
    argmax_dpp_step<0x112, 0xf>(v, i);  // row_shr:2
    argmax_dpp_step<0x114, 0xf>(v, i);  // row_shr:4
    argmax_dpp_step<0x118, 0xf>(v, i);  // row_shr:8
    argmax_dpp_step<0x142, 0xa>(v, i);  // row_bcast:15 -> rows 1,3
    argmax_dpp_step<0x143, 0xc>(v, i);  // row_bcast:31 -> rows 2,3
}

// ---------------------------------------------------------------------------
// FPS: one block per batch, 256 threads (4 waves, 1 wave/SIMD), 32 pts/thread
// in VGPRs. Per iteration: unrolled distance+argmax, DPP wave argmax, plain
// LDS slot write per wave, ONE barrier, 4-key register combine (slots double-
// buffered by t&1).
//
// CRITICAL (round-3 post-mortem): at t==0 the distances are to the MEAN and
// are used ONLY to pick the first centroid -- they must NOT be folded into
// md[] (the reference's min_d2 starts at +inf and first sees d2-to-first-
// centroid). The mean itself replicates the 1024-thread passing version's
// exact summation order so the whole selection chain is bit-identical to it.
// ---------------------------------------------------------------------------
__global__ __launch_bounds__(256, 1) void fps_kernel(const float* __restrict__ coords,
                                                     const float* __restrict__ times,
                                                     float* __restrict__ cent_ws,
                                                     float* __restrict__ cent_out,
                                                     float* __restrict__ mask_out) {
    const int b = blockIdx.x;
    const int tid = threadIdx.x;   // 0..255
    const int lane = tid & 63;
    const int wid = tid >> 6;      // physical wave 0..3

    __shared__ unsigned long long kslot[2][4];
    __shared__ float redv[16][4];

    float px[32], py[32], pz[32], pw[32], md[32];
#pragma unroll
    for (int j = 0; j < 32; ++j) {
        const int p = j * 256 + tid;
        const int n = b * 8192 + p;
        px[j] = coords[3 * n + 0];
        py[j] = coords[3 * n + 1];
        pz[j] = coords[3 * n + 2];
        pw[j] = times[n];
        md[j] = __builtin_inff();
    }

    // Mean: replicate the 1024-thread version exactly. Virtual thread
    // vt = tid + 256*q owned points p = j*1024 + vt = (4j+q)*256 + tid,
    // summed in ascending j; its wave was w = wid + 4*q; wave sums combined
    // in ascending w.
#pragma unroll
    for (int q = 0; q < 4; ++q) {
        float sx = 0.f, sy = 0.f, sz = 0.f, sw = 0.f;
#pragma unroll
        for (int j = 0; j < 8; ++j) {
            const int jj = 4 * j + q;
            sx += px[jj]; sy += py[jj]; sz += pz[jj]; sw += pw[jj];
        }
#pragma unroll
        for (int off = 32; off > 0; off >>= 1) {
            sx += __shfl_down(sx, off);
            sy += __shfl_down(sy, off);
            sz += __shfl_down(sz, off);
            sw += __shfl_down(sw, off);
        }
        if (lane == 0) {
            redv[wid + 4 * q][0] = sx;
            redv[wid + 4 * q][1] = sy;
            redv[wid + 4 * q][2] = sz;
            redv[wid + 4 * q][3] = sw;
        }
    }
    __syncthreads();
    float c0 = 0.f, c1 = 0.f, c2 = 0.f, c3 = 0.f;
#pragma unroll
    for (int w = 0; w < 16; ++w) { c0 += redv[w][0]; c1 += redv[w][1]; c2 += redv[w][2]; c3 += redv[w][3]; }
    c0 *= (1.0f / 8192.0f);
    c1 *= (1.0f / 8192.0f);
    c2 *= (1.0f / 8192.0f);
    c3 *= (1.0f / 8192.0f);

    for (int t = 0; t < 128; ++t) {
        float v = -__builtin_inff();
        int jb = 0;
        if (t == 0) {
            // distances to the mean: pick argmax only, do NOT touch md
#pragma unroll
            for (int j = 0; j < 32; ++j) {
                const float dx = px[j] - c0, dy = py[j] - c1, dz = pz[j] - c2, dw = pw[j] - c3;
                const float d2 = dx * dx + dy * dy + dz * dz + dw * dw;
                if (d2 > v) { v = d2; jb = j; }
            }
        } else {
#pragma unroll
            for (int j = 0; j < 32; ++j) {
                const float dx = px[j] - c0, dy = py[j] - c1, dz = pz[j] - c2, dw = pw[j] - c3;
                const float d2 = dx * dx + dy * dy + dz * dz + dw * dw;
                const float nm = fminf(md[j], d2);
                md[j] = nm;
                if (nm > v) { v = nm; jb = j; }
            }
        }
        int idx = jb * 256 + tid;
        argmax_wave(v, idx);
        if (lane == 63) {
            const uint32_t bv = __builtin_bit_cast(uint32_t, v);
            const uint32_t mk = (bv & 0x80000000u) ? ~bv : (bv | 0x80000000u);
            kslot[t & 1][wid] = ((unsigned long long)mk << 32) | (uint32_t)(0x7FFFFFFF - idx);
        }
        __syncthreads();
        unsigned long long kk = kslot[t & 1][0];
#pragma unroll
        for (int w = 1; w < 4; ++w) {
            const unsigned long long o = kslot[t & 1][w];
            kk = (o > kk) ? o : kk;
        }
        const int sel = 0x7FFFFFFF - (int)(uint32_t)(kk & 0xFFFFFFFFull);
        const int sn = b * 8192 + sel;
        c0 = coords[3 * sn + 0];
        c1 = coords[3 * sn + 1];
        c2 = coords[3 * sn + 2];
        c3 = times[sn];
        if (tid == (sel & 255)) {
            const int js = sel >> 8;
#pragma unroll
            for (int j = 0; j < 32; ++j)
                if (j == js) md[j] = NEG_F;
        }
        if (tid == 0) {
            const int o = (b * 128 + t) * 4;
            cent_ws[o + 0] = c0; cent_ws[o + 1] = c1; cent_ws[o + 2] = c2; cent_ws[o + 3] = c3;
            cent_out[o + 0] = c0; cent_out[o + 1] = c1; cent_out[o + 2] = c2; cent_out[o + 3] = c3;
        }
    }
    if (tid < 128) mask_out[b * 128 + tid] = 1.0f;
}

// ---------------------------------------------------------------------------
// KNN: one block per centroid (B*T=1024 blocks). d2 in LDS, 16 rounds of
// block argmin with lower-index tie-break (matches lax.top_k on -d2).
// ---------------------------------------------------------------------------
__global__ __launch_bounds__(256) void knn_kernel(const float* __restrict__ coords,
                                                  const float* __restrict__ times,
                                                  const float* __restrict__ cent,
                                                  int* __restrict__ knn) {
    __shared__ float d2s[8192];
    __shared__ float rbv[4];
    __shared__ int rbi[4];
    const int q = blockIdx.x;
    const int b = q >> 7;
    const int tid = threadIdx.x;
    const int lane = tid & 63;
    const int wid = tid >> 6;
    const float c0 = cent[q * 4 + 0], c1 = cent[q * 4 + 1], c2 = cent[q * 4 + 2], c3 = cent[q * 4 + 3];
    const float cc = c0 * c0 + c1 * c1 + c2 * c2 + c3 * c3;
    for (int p = tid; p < 8192; p += 256) {
        const int n = b * 8192 + p;
        const float x0 = coords[3 * n], x1 = coords[3 * n + 1], x2 = coords[3 * n + 2], x3 = times[n];
        const float pp = x0 * x0 + x1 * x1 + x2 * x2 + x3 * x3;
        const float dt = x0 * c0 + x1 * c1 + x2 * c2 + x3 * c3;
        d2s[p] = cc + pp - 2.0f * dt;
    }
    __syncthreads();
    for (int r = 0; r < 16; ++r) {
        float v = __builtin_inff();
        int idx = 1 << 30;
        for (int s = 0; s < 32; ++s) {
            const int p = s * 256 + tid;
            const float d = d2s[p];
            if (d < v) { v = d; idx = p; }
        }
#pragma unroll
        for (int off = 32; off > 0; off >>= 1) {
            const float ov = __shfl_down(v, off);
            const int oi = __shfl_down(idx, off);
            if (ov < v || (ov == v && oi < idx)) { v = ov; idx = oi; }
        }
        if (lane == 0) { rbv[wid] = v; rbi[wid] = idx; }
        __syncthreads();
        if (tid == 0) {
            float bb = rbv[0]; int bi = rbi[0];
            for (int w = 1; w < 4; ++w)
                if (rbv[w] < bb || (rbv[w] == bb && rbi[w] < bi)) { bb = rbv[w]; bi = rbi[w]; }
            knn[q * 16 + r] = bi;
            d2s[bi] = __builtin_inff();
        }
        __syncthreads();
    }
}

// ---------------------------------------------------------------------------
// Gather features for the 16384 knn rows into bf16 A0 (K padded 32->64 with 0)
// ---------------------------------------------------------------------------
__global__ __launch_bounds__(256) void gather_kernel(const float* __restrict__ feat,
                                                     const int* __restrict__ knn,
                                                     u16* __restrict__ A0) {
    const int idx = blockIdx.x * 256 + threadIdx.x;  // 16384*64
    const int g = idx >> 6;
    const int c = idx & 63;
    const int b = g >> 11;  // g / (T*K)=g/2048
    const int n = b * 8192 + knn[g];
    const float v = (c < 32) ? feat[(size_t)n * 32 + c] : 0.0f;
    A0[idx] = f2bf(v);
}

// All six weight transposes in ONE launch. Segment boundaries are 256-aligned
// so each block is branch-uniform.
template <int K, int N, int KP>
__device__ __forceinline__ void tp_one(const float* __restrict__ W, u16* __restrict__ Wt, int local) {
    const int n = local / KP;
    const int k = local - n * KP;
    const float v = (k < K) ? W[(size_t)k * N + n] : 0.0f;
    Wt[local] = f2bf(v);
}

__global__ __launch_bounds__(256) void transpose_all(const float* __restrict__ W0,
                                                     const float* __restrict__ W1,
                                                     const float* __restrict__ W2,
                                                     const float* __restrict__ W3,
                                                     const float* __restrict__ Wn0,
                                                     const float* __restrict__ Wn1,
                                                     u16* __restrict__ W0t, u16* __restrict__ W1t,
                                                     u16* __restrict__ W2t, u16* __restrict__ W3t,
                                                     u16* __restrict__ Wn0t, u16* __restrict__ Wn1t) {
    const int idx = blockIdx.x * 256 + threadIdx.x;
    if (idx < 16384) tp_one<32, 256, 64>(W0, W0t, idx);
    else if (idx < 147456) tp_one<256, 512, 256>(W1, W1t, idx - 16384);
    else if (idx < 540672) tp_one<512, 768, 512>(W2, W2t, idx - 147456);
    else if (idx < 1130496) tp_one<768, 768, 768>(W3, W3t, idx - 540672);
    else if (idx < 1720320) tp_one<768, 768, 768>(Wn0, Wn0t, idx - 1130496);
    else tp_one<768, 768, 768>(Wn1, Wn1t, idx - 1720320);
}

// Max-pool over K=16 gathered rows: PF (16384,768) bf16 -> pooled (1024,768)
__global__ __launch_bounds__(256) void pool_kernel(const u16* __restrict__ PF,
                                                   u16* __restrict__ pooled) {
    const int idx = blockIdx.x * 256 + threadIdx.x;  // 1024*768
    const int q = idx / 768;
    const int c = idx - q * 768;
    const u16* base = PF + (size_t)q * 16 * 768 + c;
    float best = -__builtin_inff();
    u16 bb = 0;
#pragma unroll
    for (int kk = 0; kk < 16; ++kk) {
        const u16 u = base[kk * 768];
        const float f = bf2f(u);
        if (f > best) { best = f; bb = u; }
    }
    pooled[idx] = bb;
}

// ---------------------------------------------------------------------------
// bf16 MFMA GEMM: C(M,N) = relu?(A(M,K) @ W(K,N) + bias), W given as Wt(N,K).
// 128x128 tile, BK=64, 4 waves (2x2 of 64x64), global_load_lds width 16,
// source-side XOR swizzle so ds_read_b128 is ~conflict-free.
// ---------------------------------------------------------------------------
template <int RELU, int OUTF32>
__global__ __launch_bounds__(256) void gemm_kernel(const u16* __restrict__ A,
                                                   const u16* __restrict__ Bt,
                                                   const float* __restrict__ bias,
                                                   void* __restrict__ Cv,
                                                   int M, int N, int K) {
    (void)M;
    __shared__ __align__(16) u16 As[128 * 64];
    __shared__ __align__(16) u16 Bs[128 * 64];
    const int tid = threadIdx.x;
    const int lane = tid & 63;
    const int wid = tid >> 6;
    const int brow = blockIdx.x * 128;
    const int bcol = blockIdx.y * 128;
    const int wm = (wid >> 1) * 64;
    const int wn = (wid & 1) * 64;

    f32x4 acc[4][4];
#pragma unroll
    for (int m = 0; m < 4; ++m)
#pragma unroll
        for (int n = 0; n < 4; ++n)
            acc[m][n] = f32x4{0.f, 0.f, 0.f, 0.f};

    const int srow = tid >> 3;    // 0..31
    const int schunk = tid & 7;   // 16B chunk within a 128B row
    const uint32_t lds_wave_base = (uint32_t)(wid * 1024);

    for (int k0 = 0; k0 < K; k0 += 64) {
#pragma unroll
        for (int i = 0; i < 4; ++i) {
            const int row = i * 32 + srow;
            const int sc = schunk ^ (row & 7);  // inverse-swizzled SOURCE chunk
            const u16* ga = A + (size_t)(brow + row) * K + (size_t)(k0 + sc * 8);
            const u16* gb = Bt + (size_t)(bcol + row) * K + (size_t)(k0 + sc * 8);
            const uint32_t lb = (uint32_t)(i * 4096) + lds_wave_base;  // wave-uniform base
            gload_lds16(ga, (char*)As + lb);
            gload_lds16(gb, (char*)Bs + lb);
        }
        __syncthreads();
#pragma unroll
        for (int kc = 0; kc < 2; ++kc) {
            short8 af[4], bfr[4];
#pragma unroll
            for (int m = 0; m < 4; ++m) {
                const int row = wm + m * 16 + (lane & 15);
                const int sc = (kc * 4 + (lane >> 4)) ^ (row & 7);
                af[m] = *(const short8*)(As + row * 64 + sc * 8);
            }
#pragma unroll
            for (int n = 0; n < 4; ++n) {
                const int row = wn + n * 16 + (lane & 15);
                const int sc = (kc * 4 + (lane >> 4)) ^ (row & 7);
                bfr[n] = *(const short8*)(Bs + row * 64 + sc * 8);
            }
#pragma unroll
            for (int m = 0; m < 4; ++m)
#pragma unroll
                for (int n = 0; n < 4; ++n)
                    acc[m][n] = __builtin_amdgcn_mfma_f32_16x16x32_bf16(af[m], bfr[n], acc[m][n], 0, 0, 0);
        }
        __syncthreads();
    }

#pragma unroll
    for (int m = 0; m < 4; ++m) {
        const int row0 = brow + wm + m * 16 + ((lane >> 4) << 2);
#pragma unroll
        for (int n = 0; n < 4; ++n) {
            const int col = bcol + wn + n * 16 + (lane & 15);
            const float bv = bias[col];
#pragma unroll
            for (int r = 0; r < 4; ++r) {
                float v = acc[m][n][r] + bv;
                if (RELU) v = fmaxf(v, 0.0f);
                if (OUTF32) ((float*)Cv)[(size_t)(row0 + r) * N + col] = v;
                else ((u16*)Cv)[(size_t)(row0 + r) * N + col] = f2bf(v);
            }
        }
    }
}

// ---------------------------------------------------------------------------
extern "C" void kernel_launch(void* const* d_in, const int* in_sizes, int n_in,
                              void* d_out, int out_size, void* d_ws, size_t ws_size,
                              hipStream_t stream) {
    (void)in_sizes; (void)n_in; (void)out_size; (void)ws_size;
    const float* coords = (const float*)d_in[0];
    const float* features = (const float*)d_in[1];
    const float* times = (const float*)d_in[3];
    const float* W0 = (const float*)d_in[4];
    const float* b0 = (const float*)d_in[5];
    const float* W1 = (const float*)d_in[6];
    const float* b1 = (const float*)d_in[7];
    const float* W2 = (const float*)d_in[8];
    const float* b2 = (const float*)d_in[9];
    const float* W3 = (const float*)d_in[10];
    const float* b3 = (const float*)d_in[11];
    const float* Wn0 = (const float*)d_in[12];
    const float* bn0 = (const float*)d_in[13];
    const float* Wn1 = (const float*)d_in[14];
    const float* bn1 = (const float*)d_in[15];

    char* ws = (char*)d_ws;
    float* cent = (float*)(ws + 0);           // 1024*4 f32
    int* knn = (int*)(ws + 16384);            // 16384 int
    u16* W0t = (u16*)(ws + 81920);            // 256x64
    u16* W1t = (u16*)(ws + 114688);           // 512x256
    u16* W2t = (u16*)(ws + 376832);           // 768x512
    u16* W3t = (u16*)(ws + 1163264);          // 768x768
    u16* Wn0t = (u16*)(ws + 2342912);         // 768x768
    u16* Wn1t = (u16*)(ws + 3522560);         // 768x768
    u16* bufX = (u16*)(ws + 4702208);         // 16384x768 bf16 max
    u16* bufY = (u16*)(ws + 29868032);        // 16384x768 bf16 max

    float* tokens_out = (float*)d_out;                    // (8,128,768)
    float* cent_out = (float*)d_out + 786432;             // (8,128,4)
    float* mask_out = (float*)d_out + 786432 + 4096;      // (8,128)

    // all weight transposes in one launch
    transpose_all<<<9024, 256, 0, stream>>>(W0, W1, W2, W3, Wn0, Wn1,
                                            W0t, W1t, W2t, W3t, Wn0t, Wn1t);

    // FPS -> centroids (also fills centroid + mask outputs)
    fps_kernel<<<8, 256, 0, stream>>>(coords, times, cent, cent_out, mask_out);
    // KNN top-16 per centroid
    knn_kernel<<<1024, 256, 0, stream>>>(coords, times, cent, knn);
    // gather knn rows' features (bf16, K padded to 64)
    gather_kernel<<<4096, 256, 0, stream>>>(features, knn, bufX);

    // MLP on gathered rows (M = 16384)
    gemm_kernel<1, 0><<<dim3(128, 2), 256, 0, stream>>>(bufX, W0t, b0, bufY, 16384, 256, 64);
    gemm_kernel<1, 0><<<dim3(128, 4), 256, 0, stream>>>(bufY, W1t, b1, bufX, 16384, 512, 256);
    gemm_kernel<1, 0><<<dim3(128, 6), 256, 0, stream>>>(bufX, W2t, b2, bufY, 16384, 768, 512);
    gemm_kernel<0, 0><<<dim3(128, 6), 256, 0, stream>>>(bufY, W3t, b3, bufX, 16384, 768, 768);

    // max-pool over the 16 neighbors
    pool_kernel<<<3072, 256, 0, stream>>>(bufX, bufY);

    // token MLP (M = 1024)
    gemm_kernel<1, 0><<<dim3(8, 6), 256, 0, stream>>>(bufY, Wn0t, bn0, bufX, 1024, 768, 768);
    gemm_kernel<0, 1><<<dim3(8, 6), 256, 0, stream>>>(bufX, Wn1t, bn1, tokens_out, 1024, 768, 768);
}